// Round 13
// baseline (719.947 us; speedup 1.0000x reference)
//
#include <hip/hip_runtime.h>
#include <math.h>

#define SS 2048
#define DD 1024
#define HH 16
#define CAPC 49152u   // candidate slots per head (expected ~22K at 14-bit bins)
#define LCAP 2048     // per-block LDS candidate buffer (expected ~90/block)

// quantile index: floor(0.95*(S*S-1)) = floor(3984587.85)
#define K_A 3984587u
#define K_B 3984588u
#define QFRAC 0.85f
#define WSCALE 2048.0f      // W planes pre-scaled so lo-residuals stay normal fp16
#define WSCALE_INV (1.0f/2048.0f)
#define ESHIFT 4.0f         // exp(s - thr - ESHIFT): kept P in [e^-4, ~e^6] — fp16-safe

typedef _Float16 f16x8 __attribute__((ext_vector_type(8)));
typedef _Float16 f16x4 __attribute__((ext_vector_type(4)));
typedef float    f32x4 __attribute__((ext_vector_type(4)));

__device__ __forceinline__ unsigned sortkey(float f) {
  unsigned b = __float_as_uint(f);
  return (b & 0x80000000u) ? ~b : (b | 0x80000000u);
}
__device__ __forceinline__ float inv_sortkey(unsigned u) {
  unsigned b = (u & 0x80000000u) ? (u ^ 0x80000000u) : ~u;
  return __uint_as_float(b);
}

// ---------------- input splitting ----------------
__global__ __launch_bounds__(256) void split_x(const float* __restrict__ x,
                                               _Float16* __restrict__ xh,
                                               _Float16* __restrict__ xl)
{
  const int i = blockIdx.x * 256 + threadIdx.x;   // float4 index, 524288 total
  float4 v = ((const float4*)x)[i];
  float vv[4] = {v.x, v.y, v.z, v.w};
  f16x4 h, l;
#pragma unroll
  for (int j = 0; j < 4; ++j) {
    _Float16 hh = (_Float16)vv[j];
    h[j] = hh;
    l[j] = (_Float16)(vv[j] - (float)hh);
  }
  ((f16x4*)xh)[i] = h;
  ((f16x4*)xl)[i] = l;
}

// W -> transposed hi/lo fp16 planes WT[n][k], scaled by 2048 (keeps lo normal).
__global__ __launch_bounds__(256) void split_wT(const float* __restrict__ Wq,
                                                const float* __restrict__ Wk,
                                                const float* __restrict__ Wv,
                                                const float* __restrict__ Wo,
                                                _Float16* __restrict__ wplanes)
{
  const int z = blockIdx.z;
  const float* W = (z == 0) ? Wq : (z == 1) ? Wk : (z == 2) ? Wv : Wo;
  _Float16* WhT = wplanes + (size_t)(2*z)     * (1024*1024);
  _Float16* WlT = wplanes + (size_t)(2*z + 1) * (1024*1024);
  __shared__ float tile[64][65];
  const int t  = threadIdx.x;
  const int r  = t >> 2;         // 0..63
  const int c0 = (t & 3) * 16;   // 0/16/32/48
  const int k0 = blockIdx.y * 64;
  const int n0 = blockIdx.x * 64;
#pragma unroll
  for (int j = 0; j < 4; ++j) {
    float4 v = *(const float4*)&W[(size_t)(k0 + r) * 1024 + n0 + c0 + j*4];
    tile[r][c0+j*4+0] = v.x; tile[r][c0+j*4+1] = v.y;
    tile[r][c0+j*4+2] = v.z; tile[r][c0+j*4+3] = v.w;
  }
  __syncthreads();
  f16x8 h0, h1, l0, l1;
#pragma unroll
  for (int j = 0; j < 8; ++j) {
    float v = tile[c0 + j][r] * WSCALE;
    _Float16 h = (_Float16)v;
    h0[j] = h; l0[j] = (_Float16)(v - (float)h);
  }
#pragma unroll
  for (int j = 0; j < 8; ++j) {
    float v = tile[c0 + 8 + j][r] * WSCALE;
    _Float16 h = (_Float16)v;
    h1[j] = h; l1[j] = (_Float16)(v - (float)h);
  }
  const size_t o = (size_t)(n0 + r) * 1024 + k0 + c0;
  *(f16x8*)&WhT[o]     = h0;
  *(f16x8*)&WhT[o + 8] = h1;
  *(f16x8*)&WlT[o]     = l0;
  *(f16x8*)&WlT[o + 8] = l1;
}

// ---------------- MFMA GEMM ----------------
// 512 threads = 8 waves (2M x 4N) of 64x32 wave tiles over the SAME 128x128
// block tile as round 10 (block-level reuse unchanged; waves/CU 6 -> 12).
// Register prefetch of kk+1 fragments (pure scheduling).
// Per-element MFMA chain (ascending kk; LL,HL,LH,HH) unchanged -> bitwise-identical.
// mode 0: fp16 hi/lo planes row-major (Q,K). mode 1: fp32 (final out).
// mode 2: fp16 hi/lo planes TRANSPOSED Vt[d_global][row].
__device__ __forceinline__ void gemm_mfma_body(const _Float16* __restrict__ Ah,
                                               const _Float16* __restrict__ Al,
                                               const _Float16* __restrict__ BhT,
                                               const _Float16* __restrict__ BlT,
                                               const float* __restrict__ bias,
                                               _Float16* __restrict__ Oh,
                                               _Float16* __restrict__ Ol,
                                               float* __restrict__ Of,
                                               int mode, int bm, int bn)
{
  const int wave = threadIdx.x >> 6, lane = threadIdx.x & 63;
  const int wr = wave >> 2, wc = wave & 3;   // 2 (M) x 4 (N)
  const int m0 = bm * 128 + wr * 64;
  const int n0 = bn * 128 + wc * 32;
  const int lr = lane & 15;
  const int ko = lane >> 4;

  f32x4 acc[4][2];
#pragma unroll
  for (int i = 0; i < 4; ++i)
#pragma unroll
    for (int j = 0; j < 2; ++j) acc[i][j] = (f32x4){0.f, 0.f, 0.f, 0.f};

  f16x8 aH[4], aL[4], bH[2], bL[2];
  {
    const int kof = ko*8;
#pragma unroll
    for (int i = 0; i < 4; ++i) {
      const size_t aoff = (size_t)(m0 + i*16 + lr) * 1024 + kof;
      aH[i] = *(const f16x8*)(Ah + aoff);
      aL[i] = *(const f16x8*)(Al + aoff);
    }
#pragma unroll
    for (int j = 0; j < 2; ++j) {
      const size_t boff = (size_t)(n0 + j*16 + lr) * 1024 + kof;
      bH[j] = *(const f16x8*)(BhT + boff);
      bL[j] = *(const f16x8*)(BlT + boff);
    }
  }

  for (int kk = 0; kk < 32; ++kk) {
    f16x8 nAH[4], nAL[4], nBH[2], nBL[2];
    if (kk < 31) {
      const int kof = (kk+1)*32 + ko*8;
#pragma unroll
      for (int i = 0; i < 4; ++i) {
        const size_t aoff = (size_t)(m0 + i*16 + lr) * 1024 + kof;
        nAH[i] = *(const f16x8*)(Ah + aoff);
        nAL[i] = *(const f16x8*)(Al + aoff);
      }
#pragma unroll
      for (int j = 0; j < 2; ++j) {
        const size_t boff = (size_t)(n0 + j*16 + lr) * 1024 + kof;
        nBH[j] = *(const f16x8*)(BhT + boff);
        nBL[j] = *(const f16x8*)(BlT + boff);
      }
    }
#pragma unroll
    for (int i = 0; i < 4; ++i)
#pragma unroll
      for (int j = 0; j < 2; ++j) {
        acc[i][j] = __builtin_amdgcn_mfma_f32_16x16x32_f16(aL[i], bL[j], acc[i][j], 0, 0, 0);
        acc[i][j] = __builtin_amdgcn_mfma_f32_16x16x32_f16(aH[i], bL[j], acc[i][j], 0, 0, 0);
        acc[i][j] = __builtin_amdgcn_mfma_f32_16x16x32_f16(aL[i], bH[j], acc[i][j], 0, 0, 0);
        acc[i][j] = __builtin_amdgcn_mfma_f32_16x16x32_f16(aH[i], bH[j], acc[i][j], 0, 0, 0);
      }
    if (kk < 31) {
#pragma unroll
      for (int i = 0; i < 4; ++i) { aH[i] = nAH[i]; aL[i] = nAL[i]; }
#pragma unroll
      for (int j = 0; j < 2; ++j) { bH[j] = nBH[j]; bL[j] = nBL[j]; }
    }
  }

#pragma unroll
  for (int i = 0; i < 4; ++i) {
#pragma unroll
    for (int j = 0; j < 2; ++j) {
      if (mode == 2) {
        const int col  = n0 + j*16 + lr;
        const int row0 = m0 + i*16 + ko*4;
        f16x4 hv, lv;
#pragma unroll
        for (int r = 0; r < 4; ++r) {
          const float val = acc[i][j][r] * WSCALE_INV + bias[col];
          _Float16 h = (_Float16)val;
          hv[r] = h; lv[r] = (_Float16)(val - (float)h);
        }
        *(f16x4*)&Oh[(size_t)col * 2048 + row0] = hv;
        *(f16x4*)&Ol[(size_t)col * 2048 + row0] = lv;
      } else {
#pragma unroll
        for (int r = 0; r < 4; ++r) {
          const int row = m0 + i*16 + ko*4 + r;
          const int col = n0 + j*16 + lr;
          const float val = acc[i][j][r] * WSCALE_INV + bias[col];
          if (mode == 1) {
            Of[(size_t)row * 1024 + col] = val;
          } else {
            _Float16 h = (_Float16)val;
            Oh[(size_t)row * 1024 + col] = h;
            Ol[(size_t)row * 1024 + col] = (_Float16)(val - (float)h);
          }
        }
      }
    }
  }
}

__global__ __launch_bounds__(512) void gemm_mfma_qkv(const _Float16* __restrict__ xh,
                                                     const _Float16* __restrict__ xl,
                                                     const _Float16* __restrict__ wplanes,
                                                     const float* __restrict__ bq,
                                                     const float* __restrict__ bk,
                                                     const float* __restrict__ bv,
                                                     _Float16* __restrict__ Qh,
                                                     _Float16* __restrict__ Ql,
                                                     _Float16* __restrict__ Kh,
                                                     _Float16* __restrict__ Kl,
                                                     _Float16* __restrict__ VtH,
                                                     _Float16* __restrict__ VtL)
{
  const int z = blockIdx.z;
  const _Float16* BhT = wplanes + (size_t)(2*z)     * (1024*1024);
  const _Float16* BlT = wplanes + (size_t)(2*z + 1) * (1024*1024);
  const float* bias = (z == 0) ? bq : (z == 1) ? bk : bv;
  _Float16* Oh = (z == 0) ? Qh : (z == 1) ? Kh : VtH;
  _Float16* Ol = (z == 0) ? Ql : (z == 1) ? Kl : VtL;
  gemm_mfma_body(xh, xl, BhT, BlT, bias, Oh, Ol, nullptr, (z == 2) ? 2 : 0,
                 blockIdx.y, blockIdx.x);
}

__global__ __launch_bounds__(512) void gemm_mfma_o(const _Float16* __restrict__ ctxh,
                                                   const _Float16* __restrict__ ctxl,
                                                   const _Float16* __restrict__ wplanes,
                                                   const float* __restrict__ bo,
                                                   float* __restrict__ out)
{
  gemm_mfma_body(ctxh, ctxl,
                 wplanes + (size_t)6 * (1024*1024),
                 wplanes + (size_t)7 * (1024*1024),
                 bo, nullptr, nullptr, out, 1, blockIdx.y, blockIdx.x);
}

// ---------------- pass 1: scores (recomputable MFMA chain) + fused 14-bit hist, NO store ----------------
// 512 threads = 8 waves (4m x 2n of 64x64), block tile 256x128, grid (16, 8, 16).
// The per-(row,col) MFMA chain (kk loop x LL,HL,LH,HH) is IDENTICAL in
// compact_recompute and flash_pv -> bitwise-identical scores across kernels.
__global__ __launch_bounds__(512) void scores_hist(const _Float16* __restrict__ Qh,
                                                   const _Float16* __restrict__ Ql,
                                                   const _Float16* __restrict__ Kh,
                                                   const _Float16* __restrict__ Kl,
                                                   unsigned* __restrict__ ghist)
{
  const int bn = blockIdx.x, bm = blockIdx.y, h = blockIdx.z;
  const int wave = threadIdx.x >> 6, lane = threadIdx.x & 63;
  const int wr = wave >> 1, wc = wave & 1;
  const int m0 = bm * 256 + wr * 64;
  const int n0 = bn * 128 + wc * 64;
  const int lr = lane & 15;
  const int ko = lane >> 4;

  __shared__ unsigned lh[16384];   // 64 KB
  for (int i = threadIdx.x; i < 16384; i += 512) lh[i] = 0;
  __syncthreads();

  f32x4 acc[4][4];
#pragma unroll
  for (int i = 0; i < 4; ++i)
#pragma unroll
    for (int j = 0; j < 4; ++j) acc[i][j] = (f32x4){0.f, 0.f, 0.f, 0.f};

#pragma unroll
  for (int kk = 0; kk < 2; ++kk) {
    f16x8 aH[4], aL[4], bH[4], bL[4];
#pragma unroll
    for (int i = 0; i < 4; ++i) {
      const size_t aoff = (size_t)(m0 + i*16 + lr) * 1024 + h*64 + kk*32 + ko*8;
      aH[i] = *(const f16x8*)(Qh + aoff);
      aL[i] = *(const f16x8*)(Ql + aoff);
      const size_t boff = (size_t)(n0 + i*16 + lr) * 1024 + h*64 + kk*32 + ko*8;
      bH[i] = *(const f16x8*)(Kh + boff);
      bL[i] = *(const f16x8*)(Kl + boff);
    }
#pragma unroll
    for (int i = 0; i < 4; ++i)
#pragma unroll
      for (int j = 0; j < 4; ++j) {
        acc[i][j] = __builtin_amdgcn_mfma_f32_16x16x32_f16(aL[i], bL[j], acc[i][j], 0, 0, 0);
        acc[i][j] = __builtin_amdgcn_mfma_f32_16x16x32_f16(aH[i], bL[j], acc[i][j], 0, 0, 0);
        acc[i][j] = __builtin_amdgcn_mfma_f32_16x16x32_f16(aL[i], bH[j], acc[i][j], 0, 0, 0);
        acc[i][j] = __builtin_amdgcn_mfma_f32_16x16x32_f16(aH[i], bH[j], acc[i][j], 0, 0, 0);
      }
  }

#pragma unroll
  for (int i = 0; i < 4; ++i)
#pragma unroll
    for (int j = 0; j < 4; ++j)
#pragma unroll
      for (int r = 0; r < 4; ++r) {
        const float val = acc[i][j][r] * 0.125f;
        atomicAdd(&lh[sortkey(val) >> 18], 1u);
      }
  __syncthreads();
  unsigned* __restrict__ gh = ghist + (size_t)h * 16384;
  for (int i = threadIdx.x; i < 16384; i += 512) {
    const unsigned c = lh[i];
    if (c) atomicAdd(&gh[i], c);
  }
}

// ---------------- radix select ----------------
__global__ __launch_bounds__(256) void init14(unsigned* __restrict__ ghist,
                                              unsigned* __restrict__ ccnt)
{
  int i = blockIdx.x * 256 + threadIdx.x;
  for (; i < HH * 16384; i += gridDim.x * 256) ghist[i] = 0;
  if (blockIdx.x == 0 && threadIdx.x < HH) ccnt[threadIdx.x] = 0;
}

__global__ __launch_bounds__(256) void scan14(const unsigned* __restrict__ ghist,
                                              unsigned* __restrict__ state)
{
  const int hh = blockIdx.x;
  const int t = threadIdx.x;
  __shared__ unsigned part[256];
  __shared__ unsigned out[4];
  const unsigned* __restrict__ hb = ghist + (size_t)hh * 16384;
  unsigned s = 0;
  for (int j = 0; j < 64; ++j) s += hb[t*64 + j];
  part[t] = s;
  __syncthreads();
  if (t == 0) {
    unsigned run = 0;
    for (int i = 0; i < 256; ++i) { unsigned tmp = part[i]; part[i] = run; run += tmp; }
  }
  __syncthreads();
  const unsigned cum0 = part[t];
  if (K_A >= cum0 && K_A < cum0 + s) {
    unsigned c2 = cum0;
    for (int j = 0; j < 64; ++j) {
      const unsigned c = hb[t*64 + j];
      if (K_A < c2 + c) {
        const unsigned binA = t*64 + j;
        const unsigned residA = K_A - c2;
        unsigned binB, residB;
        if (residA + 1 < c) { binB = binA; residB = residA + 1; }
        else {
          unsigned bb = binA + 1;
          while (bb < 16384 && hb[bb] == 0) ++bb;
          if (bb >= 16384) bb = 16383;  // defensive
          binB = bb; residB = 0;
        }
        out[0] = binA; out[1] = residA; out[2] = binB; out[3] = residB;
        break;
      }
      c2 += c;
    }
  }
  __syncthreads();
  if (t < 4) state[hh*4 + t] = out[t];
}

// ---------------- pass 2: recompute scores, compact candidates in bins A/B ----------------
__global__ __launch_bounds__(512) void compact_recompute(const _Float16* __restrict__ Qh,
                                                         const _Float16* __restrict__ Ql,
                                                         const _Float16* __restrict__ Kh,
                                                         const _Float16* __restrict__ Kl,
                                                         const unsigned* __restrict__ state,
                                                         unsigned* __restrict__ cand,
                                                         unsigned* __restrict__ ccnt)
{
  const int bn = blockIdx.x, bm = blockIdx.y, h = blockIdx.z;
  const int wave = threadIdx.x >> 6, lane = threadIdx.x & 63;
  const int wr = wave >> 1, wc = wave & 1;
  const int m0 = bm * 256 + wr * 64;
  const int n0 = bn * 128 + wc * 64;
  const int lr = lane & 15;
  const int ko = lane >> 4;

  __shared__ unsigned lbuf[LCAP];
  __shared__ unsigned lcnt, gbase;
  if (threadIdx.x == 0) lcnt = 0;
  __syncthreads();
  const unsigned binA = state[h*4+0];
  const unsigned binB = state[h*4+2];
  unsigned* __restrict__ mycand = cand + (size_t)h * CAPC;

  f32x4 acc[4][4];
#pragma unroll
  for (int i = 0; i < 4; ++i)
#pragma unroll
    for (int j = 0; j < 4; ++j) acc[i][j] = (f32x4){0.f, 0.f, 0.f, 0.f};

#pragma unroll
  for (int kk = 0; kk < 2; ++kk) {
    f16x8 aH[4], aL[4], bH[4], bL[4];
#pragma unroll
    for (int i = 0; i < 4; ++i) {
      const size_t aoff = (size_t)(m0 + i*16 + lr) * 1024 + h*64 + kk*32 + ko*8;
      aH[i] = *(const f16x8*)(Qh + aoff);
      aL[i] = *(const f16x8*)(Ql + aoff);
      const size_t boff = (size_t)(n0 + i*16 + lr) * 1024 + h*64 + kk*32 + ko*8;
      bH[i] = *(const f16x8*)(Kh + boff);
      bL[i] = *(const f16x8*)(Kl + boff);
    }
#pragma unroll
    for (int i = 0; i < 4; ++i)
#pragma unroll
      for (int j = 0; j < 4; ++j) {
        acc[i][j] = __builtin_amdgcn_mfma_f32_16x16x32_f16(aL[i], bL[j], acc[i][j], 0, 0, 0);
        acc[i][j] = __builtin_amdgcn_mfma_f32_16x16x32_f16(aH[i], bL[j], acc[i][j], 0, 0, 0);
        acc[i][j] = __builtin_amdgcn_mfma_f32_16x16x32_f16(aL[i], bH[j], acc[i][j], 0, 0, 0);
        acc[i][j] = __builtin_amdgcn_mfma_f32_16x16x32_f16(aH[i], bH[j], acc[i][j], 0, 0, 0);
      }
  }

#pragma unroll
  for (int i = 0; i < 4; ++i)
#pragma unroll
    for (int j = 0; j < 4; ++j)
#pragma unroll
      for (int r = 0; r < 4; ++r) {
        const float val = acc[i][j][r] * 0.125f;
        const unsigned u = sortkey(val);
        const unsigned bin = u >> 18;
        if (bin == binA || bin == binB) {
          unsigned id = atomicAdd(&lcnt, 1u);
          if (id < LCAP) lbuf[id] = u;
          else { unsigned g = atomicAdd(&ccnt[h], 1u); if (g < CAPC) mycand[g] = u; }
        }
      }
  __syncthreads();
  const unsigned n = (lcnt < LCAP) ? lcnt : LCAP;
  if (threadIdx.x == 0) gbase = n ? atomicAdd(&ccnt[h], n) : 0u;
  __syncthreads();
  const unsigned gb = gbase;
  for (unsigned i = threadIdx.x; i < n; i += 512)
    if (gb + i < CAPC) mycand[gb + i] = lbuf[i];
}

__global__ __launch_bounds__(256) void final_select_list(const unsigned* __restrict__ cand,
                                                         const unsigned* __restrict__ ccnt,
                                                         const unsigned* __restrict__ state,
                                                         float* __restrict__ thr)
{
  const int hh = blockIdx.x;
  const int t = threadIdx.x;
  __shared__ unsigned hist[256];
  __shared__ unsigned digitS, kresS;
  __shared__ float valS[2];
  unsigned n = ccnt[hh]; if (n > CAPC) n = CAPC;
  const unsigned* __restrict__ list = cand + (size_t)hh * CAPC;
  for (int tgt = 0; tgt < 2; ++tgt) {
    unsigned pfx = state[hh*4 + tgt*2];
    unsigned k   = state[hh*4 + tgt*2 + 1];
    for (int r = 0; r < 3; ++r) {
      const int s = (r == 0) ? 10 : (r == 1) ? 2 : 0;
      const int w = (r == 2) ? 2 : 8;
      const unsigned nb = 1u << w;
      hist[t] = 0;
      __syncthreads();
      for (unsigned i = t; i < n; i += 256) {
        const unsigned u = list[i];
        if ((u >> (s + w)) == pfx) atomicAdd(&hist[(u >> s) & (nb - 1)], 1u);
      }
      __syncthreads();
      if (t == 0) {
        unsigned cum = 0, b = 0;
        for (; b < nb; ++b) { const unsigned c = hist[b]; if (cum + c > k) break; cum += c; }
        if (b == nb) b = nb - 1;
        digitS = b; kresS = k - cum;
      }
      __syncthreads();
      pfx = (pfx << w) | digitS;
      k = kresS;
    }
    if (t == 0) valS[tgt] = inv_sortkey(pfx);
    __syncthreads();
  }
  if (t == 0) thr[hh] = valS[0] + QFRAC * (valS[1] - valS[0]);
}

// ---------------- pass 3: flash softmax+PV (recompute S, never materialize) ----------------
// Block = 32 Q-rows x 1 head, 4 waves (grid 64x16 = 1024 blocks = 4/CU; round-12's
// 64-row blocks gave 2/CU). Per 128-key tile: each wave computes its 32x32
// S-quadrant (identical MFMA chain -> bitwise-same scores), masks vs thr,
// P = exp(s - thr - ESHIFT), P -> padded LDS, then PV MFMA (wave owns 16 dims).
// All loop orders preserved from round 12 -> bitwise-identical output.
__global__ __launch_bounds__(256) void flash_pv(const _Float16* __restrict__ Qh,
                                                const _Float16* __restrict__ Ql,
                                                const _Float16* __restrict__ Kh,
                                                const _Float16* __restrict__ Kl,
                                                const _Float16* __restrict__ VtH,
                                                const _Float16* __restrict__ VtL,
                                                const float* __restrict__ thrArr,
                                                _Float16* __restrict__ ctxh,
                                                _Float16* __restrict__ ctxl)
{
  const int bm = blockIdx.x;          // 0..63 -> rows bm*32
  const int h  = blockIdx.y;
  const int wave = threadIdx.x >> 6, lane = threadIdx.x & 63;
  const int lr = lane & 15;
  const int ko = lane >> 4;
  const int m0 = bm * 32;
  const float thr = thrArr[h];

  __shared__ _Float16 Plds[32][136];  // pad 128->136
  __shared__ float rsLDS[32][4];

  // Q fragments are kt-invariant: hoist
  f16x8 qH[2][2], qL[2][2];
#pragma unroll
  for (int i = 0; i < 2; ++i)
#pragma unroll
    for (int kk = 0; kk < 2; ++kk) {
      const size_t aoff = (size_t)(m0 + i*16 + lr) * 1024 + h*64 + kk*32 + ko*8;
      qH[i][kk] = *(const f16x8*)(Qh + aoff);
      qL[i][kk] = *(const f16x8*)(Ql + aoff);
    }

  f32x4 oacc[2];
#pragma unroll
  for (int i = 0; i < 2; ++i) oacc[i] = (f32x4){0.f, 0.f, 0.f, 0.f};
  float rs[2][4];
#pragma unroll
  for (int i = 0; i < 2; ++i)
#pragma unroll
    for (int r = 0; r < 4; ++r) rs[i][r] = 0.f;

  const int d0 = wave * 16;   // PV: wave owns dims d0..d0+15

  for (int kt = 0; kt < 16; ++kt) {
    const int n0 = kt*128 + wave*32;   // S: wave owns keys n0..n0+31
    f32x4 sacc[2][2];
#pragma unroll
    for (int i = 0; i < 2; ++i)
#pragma unroll
      for (int j = 0; j < 2; ++j) sacc[i][j] = (f32x4){0.f, 0.f, 0.f, 0.f};

#pragma unroll
    for (int kk = 0; kk < 2; ++kk) {
      f16x8 bH[2], bL[2];
#pragma unroll
      for (int j = 0; j < 2; ++j) {
        const size_t boff = (size_t)(n0 + j*16 + lr) * 1024 + h*64 + kk*32 + ko*8;
        bH[j] = *(const f16x8*)(Kh + boff);
        bL[j] = *(const f16x8*)(Kl + boff);
      }
#pragma unroll
      for (int i = 0; i < 2; ++i)
#pragma unroll
        for (int j = 0; j < 2; ++j) {
          sacc[i][j] = __builtin_amdgcn_mfma_f32_16x16x32_f16(qL[i][kk], bL[j], sacc[i][j], 0, 0, 0);
          sacc[i][j] = __builtin_amdgcn_mfma_f32_16x16x32_f16(qH[i][kk], bL[j], sacc[i][j], 0, 0, 0);
          sacc[i][j] = __builtin_amdgcn_mfma_f32_16x16x32_f16(qL[i][kk], bH[j], sacc[i][j], 0, 0, 0);
          sacc[i][j] = __builtin_amdgcn_mfma_f32_16x16x32_f16(qH[i][kk], bH[j], sacc[i][j], 0, 0, 0);
        }
    }

    // mask + exp + P->LDS + rowsum partials
#pragma unroll
    for (int i = 0; i < 2; ++i)
#pragma unroll
      for (int j = 0; j < 2; ++j)
#pragma unroll
        for (int r = 0; r < 4; ++r) {
          const float val = sacc[i][j][r] * 0.125f;
          const float p = (val >= thr) ? __expf(val - thr - ESHIFT) : 0.f;
          rs[i][r] += p;
          Plds[i*16 + ko*4 + r][wave*32 + j*16 + lr] = (_Float16)p;
        }
    __syncthreads();

    // PV: oacc[i] over dims d0+lr, keys kt*128..+127
#pragma unroll
    for (int kk2 = 0; kk2 < 4; ++kk2) {
      f16x8 pa[2];
#pragma unroll
      for (int i = 0; i < 2; ++i)
        pa[i] = *(const f16x8*)&Plds[i*16 + lr][kk2*32 + ko*8];
      const size_t vo = (size_t)(h*64 + d0 + lr) * 2048 + kt*128 + kk2*32 + ko*8;
      const f16x8 vH = *(const f16x8*)(VtH + vo);
      const f16x8 vL = *(const f16x8*)(VtL + vo);
#pragma unroll
      for (int i = 0; i < 2; ++i) {
        oacc[i] = __builtin_amdgcn_mfma_f32_16x16x32_f16(pa[i], vL, oacc[i], 0, 0, 0);
        oacc[i] = __builtin_amdgcn_mfma_f32_16x16x32_f16(pa[i], vH, oacc[i], 0, 0, 0);
      }
    }
    __syncthreads();   // before next kt overwrites Plds
  }

  // rowsum: reduce across the 16 lanes of each ko-group, then across waves
#pragma unroll
  for (int i = 0; i < 2; ++i)
#pragma unroll
    for (int r = 0; r < 4; ++r) {
      float v = rs[i][r];
      v += __shfl_xor(v, 1); v += __shfl_xor(v, 2);
      v += __shfl_xor(v, 4); v += __shfl_xor(v, 8);
      rs[i][r] = v;
    }
  if (lr == 0) {
#pragma unroll
    for (int i = 0; i < 2; ++i)
#pragma unroll
      for (int r = 0; r < 4; ++r)
        rsLDS[i*16 + ko*4 + r][wave] = rs[i][r];
  }
  __syncthreads();

  // normalize + fp16-split store of ctx
#pragma unroll
  for (int i = 0; i < 2; ++i)
#pragma unroll
    for (int r = 0; r < 4; ++r) {
      const int lrow = i*16 + ko*4 + r;
      const float tot = rsLDS[lrow][0] + rsLDS[lrow][1] + rsLDS[lrow][2] + rsLDS[lrow][3];
      const float val = oacc[i][r] / tot;
      const size_t oidx = (size_t)(m0 + lrow) * 1024 + h*64 + d0 + lr;
      _Float16 hv = (_Float16)val;
      ctxh[oidx] = hv;
      ctxl[oidx] = (_Float16)(val - (float)hv);
    }
}

// ---------------- host ----------------
extern "C" void kernel_launch(void* const* d_in, const int* in_sizes, int n_in,
                              void* d_out, int out_size, void* d_ws, size_t ws_size,
                              hipStream_t stream)
{
  const float* x  = (const float*)d_in[0];
  const float* Wq = (const float*)d_in[1];
  const float* bq = (const float*)d_in[2];
  const float* Wk = (const float*)d_in[3];
  const float* bk = (const float*)d_in[4];
  const float* Wv = (const float*)d_in[5];
  const float* bv = (const float*)d_in[6];
  const float* Wo = (const float*)d_in[7];
  const float* bo = (const float*)d_in[8];
  float* out = (float*)d_out;
  char*  ws  = (char*)d_ws;

  const size_t MB = 1u << 20;
  _Float16* xh      = (_Float16*)(ws + 0*MB);
  _Float16* xl      = (_Float16*)(ws + 4*MB);
  _Float16* wplanes = (_Float16*)(ws + 8*MB);    // 8 x 2 MiB transposed W planes
  _Float16* Qh      = (_Float16*)(ws + 24*MB);
  _Float16* Ql      = (_Float16*)(ws + 28*MB);
  _Float16* Kh      = (_Float16*)(ws + 32*MB);
  _Float16* Kl      = (_Float16*)(ws + 36*MB);
  _Float16* VtH     = (_Float16*)(ws + 40*MB);   // [1024 dims][2048 rows]
  _Float16* VtL     = (_Float16*)(ws + 44*MB);
  _Float16* ctxh    = (_Float16*)(ws + 48*MB);
  _Float16* ctxl    = (_Float16*)(ws + 52*MB);
  const size_t base = 56*MB;
  unsigned* state = (unsigned*)(ws + base);
  float*    thr   = (float*)(ws + base + 4096);
  unsigned* ccnt  = (unsigned*)(ws + base + 8192);
  unsigned* ghist = (unsigned*)(ws + base + 16384);           // 1 MiB
  unsigned* cand  = (unsigned*)(ws + base + 16384 + 1048576); // 3 MiB

  split_x<<<2048, 256, 0, stream>>>(x, xh, xl);
  split_wT<<<dim3(16, 16, 4), 256, 0, stream>>>(Wq, Wk, Wv, Wo, wplanes);
  gemm_mfma_qkv<<<dim3(8, 16, 3), 512, 0, stream>>>(xh, xl, wplanes, bq, bk, bv,
                                                    Qh, Ql, Kh, Kl, VtH, VtL);

  init14<<<256, 256, 0, stream>>>(ghist, ccnt);
  scores_hist<<<dim3(16, 8, HH), 512, 0, stream>>>(Qh, Ql, Kh, Kl, ghist);
  scan14<<<HH, 256, 0, stream>>>(ghist, state);
  compact_recompute<<<dim3(16, 8, HH), 512, 0, stream>>>(Qh, Ql, Kh, Kl, state, cand, ccnt);
  final_select_list<<<HH, 256, 0, stream>>>(cand, ccnt, state, thr);
  flash_pv<<<dim3(64, HH), 256, 0, stream>>>(Qh, Ql, Kh, Kl, VtH, VtL, thr, ctxh, ctxl);

  gemm_mfma_o<<<dim3(8, 16), 512, 0, stream>>>(ctxh, ctxl, wplanes, bo, out);
}

// Round 14
// 578.744 us; speedup vs baseline: 1.2440x; 1.2440x over previous
//
#include <hip/hip_runtime.h>
#include <math.h>

#define SS 2048
#define DD 1024
#define HH 16
#define CAPC 49152u   // candidate slots per head (expected ~22K at 14-bit bins)
#define LCAP 2048     // per-block LDS candidate buffer (expected ~90/block)

// quantile index: floor(0.95*(S*S-1)) = floor(3984587.85)
#define K_A 3984587u
#define K_B 3984588u
#define QFRAC 0.85f
#define WSCALE 2048.0f      // W planes pre-scaled so lo-residuals stay normal fp16
#define WSCALE_INV (1.0f/2048.0f)
#define ESHIFT 4.0f         // exp(s - thr - ESHIFT): kept P in [e^-4, ~e^6] — fp16-safe
#define PLANE 2097152       // floats per 2048x1024 fp32 partial plane (8 MiB)

typedef _Float16 f16x8 __attribute__((ext_vector_type(8)));
typedef _Float16 f16x4 __attribute__((ext_vector_type(4)));
typedef float    f32x4 __attribute__((ext_vector_type(4)));

__device__ __forceinline__ unsigned sortkey(float f) {
  unsigned b = __float_as_uint(f);
  return (b & 0x80000000u) ? ~b : (b | 0x80000000u);
}
__device__ __forceinline__ float inv_sortkey(unsigned u) {
  unsigned b = (u & 0x80000000u) ? (u ^ 0x80000000u) : ~u;
  return __uint_as_float(b);
}

// ---------------- input splitting ----------------
__global__ __launch_bounds__(256) void split_x(const float* __restrict__ x,
                                               _Float16* __restrict__ xh,
                                               _Float16* __restrict__ xl)
{
  const int i = blockIdx.x * 256 + threadIdx.x;   // float4 index, 524288 total
  float4 v = ((const float4*)x)[i];
  float vv[4] = {v.x, v.y, v.z, v.w};
  f16x4 h, l;
#pragma unroll
  for (int j = 0; j < 4; ++j) {
    _Float16 hh = (_Float16)vv[j];
    h[j] = hh;
    l[j] = (_Float16)(vv[j] - (float)hh);
  }
  ((f16x4*)xh)[i] = h;
  ((f16x4*)xl)[i] = l;
}

// W -> transposed hi/lo fp16 planes WT[n][k], scaled by 2048 (keeps lo normal).
__global__ __launch_bounds__(256) void split_wT(const float* __restrict__ Wq,
                                                const float* __restrict__ Wk,
                                                const float* __restrict__ Wv,
                                                const float* __restrict__ Wo,
                                                _Float16* __restrict__ wplanes)
{
  const int z = blockIdx.z;
  const float* W = (z == 0) ? Wq : (z == 1) ? Wk : (z == 2) ? Wv : Wo;
  _Float16* WhT = wplanes + (size_t)(2*z)     * (1024*1024);
  _Float16* WlT = wplanes + (size_t)(2*z + 1) * (1024*1024);
  __shared__ float tile[64][65];
  const int t  = threadIdx.x;
  const int r  = t >> 2;         // 0..63
  const int c0 = (t & 3) * 16;   // 0/16/32/48
  const int k0 = blockIdx.y * 64;
  const int n0 = blockIdx.x * 64;
#pragma unroll
  for (int j = 0; j < 4; ++j) {
    float4 v = *(const float4*)&W[(size_t)(k0 + r) * 1024 + n0 + c0 + j*4];
    tile[r][c0+j*4+0] = v.x; tile[r][c0+j*4+1] = v.y;
    tile[r][c0+j*4+2] = v.z; tile[r][c0+j*4+3] = v.w;
  }
  __syncthreads();
  f16x8 h0, h1, l0, l1;
#pragma unroll
  for (int j = 0; j < 8; ++j) {
    float v = tile[c0 + j][r] * WSCALE;
    _Float16 h = (_Float16)v;
    h0[j] = h; l0[j] = (_Float16)(v - (float)h);
  }
#pragma unroll
  for (int j = 0; j < 8; ++j) {
    float v = tile[c0 + 8 + j][r] * WSCALE;
    _Float16 h = (_Float16)v;
    h1[j] = h; l1[j] = (_Float16)(v - (float)h);
  }
  const size_t o = (size_t)(n0 + r) * 1024 + k0 + c0;
  *(f16x8*)&WhT[o]     = h0;
  *(f16x8*)&WhT[o + 8] = h1;
  *(f16x8*)&WlT[o]     = l0;
  *(f16x8*)&WlT[o + 8] = l1;
}

// ---------------- split-K MFMA GEMM partial ----------------
// Round-12-proven geometry: 256 threads = 4 waves (2x2) of 64x64 wave tiles,
// 128x128 block tile. kh selects K half [kh*512, kh*512+512). Raw fp32 partial
// out (no scale/bias — applied in combine). Ascending-kk LL,HL,LH,HH chain.
__device__ __forceinline__ void gemm_mfma_part(const _Float16* __restrict__ Ah,
                                               const _Float16* __restrict__ Al,
                                               const _Float16* __restrict__ BhT,
                                               const _Float16* __restrict__ BlT,
                                               float* __restrict__ pout,
                                               int bm, int bn, int kh)
{
  const int wave = threadIdx.x >> 6, lane = threadIdx.x & 63;
  const int wr = wave >> 1, wc = wave & 1;
  const int m0 = bm * 128 + wr * 64;
  const int n0 = bn * 128 + wc * 64;
  const int lr = lane & 15;
  const int ko = lane >> 4;

  f32x4 acc[4][4];
#pragma unroll
  for (int i = 0; i < 4; ++i)
#pragma unroll
    for (int j = 0; j < 4; ++j) acc[i][j] = (f32x4){0.f, 0.f, 0.f, 0.f};

  for (int kk = kh*16; kk < kh*16 + 16; ++kk) {
    const int kof = kk*32 + ko*8;
    f16x8 aH[4], aL[4], bH[4], bL[4];
#pragma unroll
    for (int i = 0; i < 4; ++i) {
      const size_t aoff = (size_t)(m0 + i*16 + lr) * 1024 + kof;
      aH[i] = *(const f16x8*)(Ah + aoff);
      aL[i] = *(const f16x8*)(Al + aoff);
      const size_t boff = (size_t)(n0 + i*16 + lr) * 1024 + kof;
      bH[i] = *(const f16x8*)(BhT + boff);
      bL[i] = *(const f16x8*)(BlT + boff);
    }
#pragma unroll
    for (int i = 0; i < 4; ++i)
#pragma unroll
      for (int j = 0; j < 4; ++j) {
        acc[i][j] = __builtin_amdgcn_mfma_f32_16x16x32_f16(aL[i], bL[j], acc[i][j], 0, 0, 0);
        acc[i][j] = __builtin_amdgcn_mfma_f32_16x16x32_f16(aH[i], bL[j], acc[i][j], 0, 0, 0);
        acc[i][j] = __builtin_amdgcn_mfma_f32_16x16x32_f16(aL[i], bH[j], acc[i][j], 0, 0, 0);
        acc[i][j] = __builtin_amdgcn_mfma_f32_16x16x32_f16(aH[i], bH[j], acc[i][j], 0, 0, 0);
      }
  }

#pragma unroll
  for (int i = 0; i < 4; ++i)
#pragma unroll
    for (int j = 0; j < 4; ++j)
#pragma unroll
      for (int r = 0; r < 4; ++r) {
        const int row = m0 + i*16 + ko*4 + r;
        const int col = n0 + j*16 + lr;
        pout[(size_t)row * 1024 + col] = acc[i][j][r];
      }
}

__global__ __launch_bounds__(256) void gemm_qkv_part(const _Float16* __restrict__ xh,
                                                     const _Float16* __restrict__ xl,
                                                     const _Float16* __restrict__ wplanes,
                                                     float* __restrict__ pbuf)
{
  const int z = blockIdx.z;           // 0..5: gemm_id*2 + khalf
  const int g = z >> 1, kh = z & 1;
  const _Float16* BhT = wplanes + (size_t)(2*g)     * (1024*1024);
  const _Float16* BlT = wplanes + (size_t)(2*g + 1) * (1024*1024);
  gemm_mfma_part(xh, xl, BhT, BlT, pbuf + (size_t)z * PLANE,
                 blockIdx.y, blockIdx.x, kh);
}

__global__ __launch_bounds__(256) void gemm_o_part(const _Float16* __restrict__ ctxh,
                                                   const _Float16* __restrict__ ctxl,
                                                   const _Float16* __restrict__ wplanes,
                                                   float* __restrict__ pO)
{
  const int kh = blockIdx.z;          // 0..1
  gemm_mfma_part(ctxh, ctxl,
                 wplanes + (size_t)6 * (1024*1024),
                 wplanes + (size_t)7 * (1024*1024),
                 pO + (size_t)kh * PLANE, blockIdx.y, blockIdx.x, kh);
}

// ---------------- combine kernels ----------------
// Q/K: val = (p0+p1)*WSCALE_INV + bias; fp16 hi/lo split (same split code as r12).
__global__ __launch_bounds__(256) void combine_qk(const float* __restrict__ pbuf,
                                                  const float* __restrict__ bq,
                                                  const float* __restrict__ bk,
                                                  _Float16* __restrict__ Qh,
                                                  _Float16* __restrict__ Ql,
                                                  _Float16* __restrict__ Kh,
                                                  _Float16* __restrict__ Kl)
{
  const int which = blockIdx.y;       // 0=Q, 1=K
  const float* p0 = pbuf + (size_t)(which*2)     * PLANE;
  const float* p1 = pbuf + (size_t)(which*2 + 1) * PLANE;
  const float* bias = which ? bk : bq;
  _Float16* Oh = which ? Kh : Qh;
  _Float16* Ol = which ? Kl : Ql;
  const int i = blockIdx.x * 256 + threadIdx.x;   // f4 index, 524288
  const int coloff = (i & 255) * 4;
  float4 a = ((const float4*)p0)[i];
  float4 b = ((const float4*)p1)[i];
  float av[4] = {a.x, a.y, a.z, a.w};
  float bv[4] = {b.x, b.y, b.z, b.w};
  f16x4 h, l;
#pragma unroll
  for (int j = 0; j < 4; ++j) {
    const float val = (av[j] + bv[j]) * WSCALE_INV + bias[coloff + j];
    _Float16 hh = (_Float16)val;
    h[j] = hh;
    l[j] = (_Float16)(val - (float)hh);
  }
  ((f16x4*)Oh)[i] = h;
  ((f16x4*)Ol)[i] = l;
}

// V: combine + transpose to Vt[dim][row] hi/lo planes (LDS 64x64 tile).
__global__ __launch_bounds__(256) void combine_vT(const float* __restrict__ pbuf,
                                                  const float* __restrict__ bv,
                                                  _Float16* __restrict__ VtH,
                                                  _Float16* __restrict__ VtL)
{
  const float* p0 = pbuf + (size_t)4 * PLANE;
  const float* p1 = pbuf + (size_t)5 * PLANE;
  __shared__ float tile[64][65];
  const int t  = threadIdx.x;
  const int d0 = blockIdx.x * 64;     // dim tile
  const int m0 = blockIdx.y * 64;     // row tile
  {
    const int r  = t >> 2;            // row 0..63
    const int c0 = (t & 3) * 16;
#pragma unroll
    for (int j = 0; j < 4; ++j) {
      const size_t o = (size_t)(m0 + r) * 1024 + d0 + c0 + j*4;
      float4 a = *(const float4*)(p0 + o);
      float4 b = *(const float4*)(p1 + o);
      tile[r][c0+j*4+0] = (a.x + b.x) * WSCALE_INV + bv[d0 + c0 + j*4 + 0];
      tile[r][c0+j*4+1] = (a.y + b.y) * WSCALE_INV + bv[d0 + c0 + j*4 + 1];
      tile[r][c0+j*4+2] = (a.z + b.z) * WSCALE_INV + bv[d0 + c0 + j*4 + 2];
      tile[r][c0+j*4+3] = (a.w + b.w) * WSCALE_INV + bv[d0 + c0 + j*4 + 3];
    }
  }
  __syncthreads();
  {
    const int d  = t >> 2;            // dim 0..63
    const int rg = (t & 3) * 16;      // row group
#pragma unroll
    for (int j = 0; j < 4; ++j) {
      f16x4 hv, lv;
#pragma unroll
      for (int r = 0; r < 4; ++r) {
        const float val = tile[rg + j*4 + r][d];
        _Float16 h = (_Float16)val;
        hv[r] = h; lv[r] = (_Float16)(val - (float)h);
      }
      const size_t o = (size_t)(d0 + d) * 2048 + m0 + rg + j*4;
      *(f16x4*)&VtH[o] = hv;
      *(f16x4*)&VtL[o] = lv;
    }
  }
}

// final out: fp32
__global__ __launch_bounds__(256) void combine_o(const float* __restrict__ pO,
                                                 const float* __restrict__ bo,
                                                 float* __restrict__ out)
{
  const float* p0 = pO;
  const float* p1 = pO + (size_t)1 * PLANE;
  const int i = blockIdx.x * 256 + threadIdx.x;
  const int coloff = (i & 255) * 4;
  float4 a = ((const float4*)p0)[i];
  float4 b = ((const float4*)p1)[i];
  float4 o;
  o.x = (a.x + b.x) * WSCALE_INV + bo[coloff + 0];
  o.y = (a.y + b.y) * WSCALE_INV + bo[coloff + 1];
  o.z = (a.z + b.z) * WSCALE_INV + bo[coloff + 2];
  o.w = (a.w + b.w) * WSCALE_INV + bo[coloff + 3];
  ((float4*)out)[i] = o;
}

// ctx: (p0+p1) / (rs0+rs1), then fp16 hi/lo split.
__global__ __launch_bounds__(256) void combine_ctx(const float* __restrict__ pctx,
                                                   const float* __restrict__ prs,
                                                   _Float16* __restrict__ ctxh,
                                                   _Float16* __restrict__ ctxl)
{
  const float* p0 = pctx;
  const float* p1 = pctx + (size_t)1 * PLANE;
  const int i = blockIdx.x * 256 + threadIdx.x;   // f4 index, 524288
  const int row = i >> 8;
  const int cd  = (i & 255) * 4;
  const int h   = cd >> 6;
  const float rs = prs[h*2048 + row] + prs[32768 + h*2048 + row];
  float4 a = ((const float4*)p0)[i];
  float4 b = ((const float4*)p1)[i];
  float av[4] = {a.x, a.y, a.z, a.w};
  float bv[4] = {b.x, b.y, b.z, b.w};
  f16x4 hh, ll;
#pragma unroll
  for (int j = 0; j < 4; ++j) {
    const float val = (av[j] + bv[j]) / rs;
    _Float16 hv = (_Float16)val;
    hh[j] = hv;
    ll[j] = (_Float16)(val - (float)hv);
  }
  ((f16x4*)ctxh)[i] = hh;
  ((f16x4*)ctxl)[i] = ll;
}

// ---------------- pass 1: scores (recomputable MFMA chain) + fused 14-bit hist, NO store ----------------
__global__ __launch_bounds__(512) void scores_hist(const _Float16* __restrict__ Qh,
                                                   const _Float16* __restrict__ Ql,
                                                   const _Float16* __restrict__ Kh,
                                                   const _Float16* __restrict__ Kl,
                                                   unsigned* __restrict__ ghist)
{
  const int bn = blockIdx.x, bm = blockIdx.y, h = blockIdx.z;
  const int wave = threadIdx.x >> 6, lane = threadIdx.x & 63;
  const int wr = wave >> 1, wc = wave & 1;
  const int m0 = bm * 256 + wr * 64;
  const int n0 = bn * 128 + wc * 64;
  const int lr = lane & 15;
  const int ko = lane >> 4;

  __shared__ unsigned lh[16384];   // 64 KB
  for (int i = threadIdx.x; i < 16384; i += 512) lh[i] = 0;
  __syncthreads();

  f32x4 acc[4][4];
#pragma unroll
  for (int i = 0; i < 4; ++i)
#pragma unroll
    for (int j = 0; j < 4; ++j) acc[i][j] = (f32x4){0.f, 0.f, 0.f, 0.f};

#pragma unroll
  for (int kk = 0; kk < 2; ++kk) {
    f16x8 aH[4], aL[4], bH[4], bL[4];
#pragma unroll
    for (int i = 0; i < 4; ++i) {
      const size_t aoff = (size_t)(m0 + i*16 + lr) * 1024 + h*64 + kk*32 + ko*8;
      aH[i] = *(const f16x8*)(Qh + aoff);
      aL[i] = *(const f16x8*)(Ql + aoff);
      const size_t boff = (size_t)(n0 + i*16 + lr) * 1024 + h*64 + kk*32 + ko*8;
      bH[i] = *(const f16x8*)(Kh + boff);
      bL[i] = *(const f16x8*)(Kl + boff);
    }
#pragma unroll
    for (int i = 0; i < 4; ++i)
#pragma unroll
      for (int j = 0; j < 4; ++j) {
        acc[i][j] = __builtin_amdgcn_mfma_f32_16x16x32_f16(aL[i], bL[j], acc[i][j], 0, 0, 0);
        acc[i][j] = __builtin_amdgcn_mfma_f32_16x16x32_f16(aH[i], bL[j], acc[i][j], 0, 0, 0);
        acc[i][j] = __builtin_amdgcn_mfma_f32_16x16x32_f16(aL[i], bH[j], acc[i][j], 0, 0, 0);
        acc[i][j] = __builtin_amdgcn_mfma_f32_16x16x32_f16(aH[i], bH[j], acc[i][j], 0, 0, 0);
      }
  }

#pragma unroll
  for (int i = 0; i < 4; ++i)
#pragma unroll
    for (int j = 0; j < 4; ++j)
#pragma unroll
      for (int r = 0; r < 4; ++r) {
        const float val = acc[i][j][r] * 0.125f;
        atomicAdd(&lh[sortkey(val) >> 18], 1u);
      }
  __syncthreads();
  unsigned* __restrict__ gh = ghist + (size_t)h * 16384;
  for (int i = threadIdx.x; i < 16384; i += 512) {
    const unsigned c = lh[i];
    if (c) atomicAdd(&gh[i], c);
  }
}

// ---------------- radix select ----------------
__global__ __launch_bounds__(256) void init14(unsigned* __restrict__ ghist,
                                              unsigned* __restrict__ ccnt)
{
  int i = blockIdx.x * 256 + threadIdx.x;
  for (; i < HH * 16384; i += gridDim.x * 256) ghist[i] = 0;
  if (blockIdx.x == 0 && threadIdx.x < HH) ccnt[threadIdx.x] = 0;
}

__global__ __launch_bounds__(256) void scan14(const unsigned* __restrict__ ghist,
                                              unsigned* __restrict__ state)
{
  const int hh = blockIdx.x;
  const int t = threadIdx.x;
  __shared__ unsigned part[256];
  __shared__ unsigned out[4];
  const unsigned* __restrict__ hb = ghist + (size_t)hh * 16384;
  unsigned s = 0;
  for (int j = 0; j < 64; ++j) s += hb[t*64 + j];
  part[t] = s;
  __syncthreads();
  if (t == 0) {
    unsigned run = 0;
    for (int i = 0; i < 256; ++i) { unsigned tmp = part[i]; part[i] = run; run += tmp; }
  }
  __syncthreads();
  const unsigned cum0 = part[t];
  if (K_A >= cum0 && K_A < cum0 + s) {
    unsigned c2 = cum0;
    for (int j = 0; j < 64; ++j) {
      const unsigned c = hb[t*64 + j];
      if (K_A < c2 + c) {
        const unsigned binA = t*64 + j;
        const unsigned residA = K_A - c2;
        unsigned binB, residB;
        if (residA + 1 < c) { binB = binA; residB = residA + 1; }
        else {
          unsigned bb = binA + 1;
          while (bb < 16384 && hb[bb] == 0) ++bb;
          if (bb >= 16384) bb = 16383;  // defensive
          binB = bb; residB = 0;
        }
        out[0] = binA; out[1] = residA; out[2] = binB; out[3] = residB;
        break;
      }
      c2 += c;
    }
  }
  __syncthreads();
  if (t < 4) state[hh*4 + t] = out[t];
}

// ---------------- pass 2: recompute scores, compact candidates in bins A/B ----------------
__global__ __launch_bounds__(512) void compact_recompute(const _Float16* __restrict__ Qh,
                                                         const _Float16* __restrict__ Ql,
                                                         const _Float16* __restrict__ Kh,
                                                         const _Float16* __restrict__ Kl,
                                                         const unsigned* __restrict__ state,
                                                         unsigned* __restrict__ cand,
                                                         unsigned* __restrict__ ccnt)
{
  const int bn = blockIdx.x, bm = blockIdx.y, h = blockIdx.z;
  const int wave = threadIdx.x >> 6, lane = threadIdx.x & 63;
  const int wr = wave >> 1, wc = wave & 1;
  const int m0 = bm * 256 + wr * 64;
  const int n0 = bn * 128 + wc * 64;
  const int lr = lane & 15;
  const int ko = lane >> 4;

  __shared__ unsigned lbuf[LCAP];
  __shared__ unsigned lcnt, gbase;
  if (threadIdx.x == 0) lcnt = 0;
  __syncthreads();
  const unsigned binA = state[h*4+0];
  const unsigned binB = state[h*4+2];
  unsigned* __restrict__ mycand = cand + (size_t)h * CAPC;

  f32x4 acc[4][4];
#pragma unroll
  for (int i = 0; i < 4; ++i)
#pragma unroll
    for (int j = 0; j < 4; ++j) acc[i][j] = (f32x4){0.f, 0.f, 0.f, 0.f};

#pragma unroll
  for (int kk = 0; kk < 2; ++kk) {
    f16x8 aH[4], aL[4], bH[4], bL[4];
#pragma unroll
    for (int i = 0; i < 4; ++i) {
      const size_t aoff = (size_t)(m0 + i*16 + lr) * 1024 + h*64 + kk*32 + ko*8;
      aH[i] = *(const f16x8*)(Qh + aoff);
      aL[i] = *(const f16x8*)(Ql + aoff);
      const size_t boff = (size_t)(n0 + i*16 + lr) * 1024 + h*64 + kk*32 + ko*8;
      bH[i] = *(const f16x8*)(Kh + boff);
      bL[i] = *(const f16x8*)(Kl + boff);
    }
#pragma unroll
    for (int i = 0; i < 4; ++i)
#pragma unroll
      for (int j = 0; j < 4; ++j) {
        acc[i][j] = __builtin_amdgcn_mfma_f32_16x16x32_f16(aL[i], bL[j], acc[i][j], 0, 0, 0);
        acc[i][j] = __builtin_amdgcn_mfma_f32_16x16x32_f16(aH[i], bL[j], acc[i][j], 0, 0, 0);
        acc[i][j] = __builtin_amdgcn_mfma_f32_16x16x32_f16(aL[i], bH[j], acc[i][j], 0, 0, 0);
        acc[i][j] = __builtin_amdgcn_mfma_f32_16x16x32_f16(aH[i], bH[j], acc[i][j], 0, 0, 0);
      }
  }

#pragma unroll
  for (int i = 0; i < 4; ++i)
#pragma unroll
    for (int j = 0; j < 4; ++j)
#pragma unroll
      for (int r = 0; r < 4; ++r) {
        const float val = acc[i][j][r] * 0.125f;
        const unsigned u = sortkey(val);
        const unsigned bin = u >> 18;
        if (bin == binA || bin == binB) {
          unsigned id = atomicAdd(&lcnt, 1u);
          if (id < LCAP) lbuf[id] = u;
          else { unsigned g = atomicAdd(&ccnt[h], 1u); if (g < CAPC) mycand[g] = u; }
        }
      }
  __syncthreads();
  const unsigned n = (lcnt < LCAP) ? lcnt : LCAP;
  if (threadIdx.x == 0) gbase = n ? atomicAdd(&ccnt[h], n) : 0u;
  __syncthreads();
  const unsigned gb = gbase;
  for (unsigned i = threadIdx.x; i < n; i += 512)
    if (gb + i < CAPC) mycand[gb + i] = lbuf[i];
}

__global__ __launch_bounds__(256) void final_select_list(const unsigned* __restrict__ cand,
                                                         const unsigned* __restrict__ ccnt,
                                                         const unsigned* __restrict__ state,
                                                         float* __restrict__ thr)
{
  const int hh = blockIdx.x;
  const int t = threadIdx.x;
  __shared__ unsigned hist[256];
  __shared__ unsigned digitS, kresS;
  __shared__ float valS[2];
  unsigned n = ccnt[hh]; if (n > CAPC) n = CAPC;
  const unsigned* __restrict__ list = cand + (size_t)hh * CAPC;
  for (int tgt = 0; tgt < 2; ++tgt) {
    unsigned pfx = state[hh*4 + tgt*2];
    unsigned k   = state[hh*4 + tgt*2 + 1];
    for (int r = 0; r < 3; ++r) {
      const int s = (r == 0) ? 10 : (r == 1) ? 2 : 0;
      const int w = (r == 2) ? 2 : 8;
      const unsigned nb = 1u << w;
      hist[t] = 0;
      __syncthreads();
      for (unsigned i = t; i < n; i += 256) {
        const unsigned u = list[i];
        if ((u >> (s + w)) == pfx) atomicAdd(&hist[(u >> s) & (nb - 1)], 1u);
      }
      __syncthreads();
      if (t == 0) {
        unsigned cum = 0, b = 0;
        for (; b < nb; ++b) { const unsigned c = hist[b]; if (cum + c > k) break; cum += c; }
        if (b == nb) b = nb - 1;
        digitS = b; kresS = k - cum;
      }
      __syncthreads();
      pfx = (pfx << w) | digitS;
      k = kresS;
    }
    if (t == 0) valS[tgt] = inv_sortkey(pfx);
    __syncthreads();
  }
  if (t == 0) thr[hh] = valS[0] + QFRAC * (valS[1] - valS[0]);
}

// ---------------- pass 3: flash softmax+PV, key-split over 2 halves ----------------
// Round-12-proven 64-row blocks; blockIdx.z = key-half (kt in [half*8, half*8+8)).
// Per-block K/V traffic halves, so total K/V traffic unchanged; blocks 512 -> 1024
// (4/CU). Partial O (raw fp32) + partial rowsums; combine_ctx normalizes.
__global__ __launch_bounds__(256) void flash_pv_sk(const _Float16* __restrict__ Qh,
                                                   const _Float16* __restrict__ Ql,
                                                   const _Float16* __restrict__ Kh,
                                                   const _Float16* __restrict__ Kl,
                                                   const _Float16* __restrict__ VtH,
                                                   const _Float16* __restrict__ VtL,
                                                   const float* __restrict__ thrArr,
                                                   float* __restrict__ pctx,
                                                   float* __restrict__ prs)
{
  const int bm = blockIdx.x;          // 0..31 -> rows bm*64
  const int h  = blockIdx.y;
  const int half = blockIdx.z;        // 0..1
  const int wave = threadIdx.x >> 6, lane = threadIdx.x & 63;
  const int lr = lane & 15;
  const int ko = lane >> 4;
  const int m0 = bm * 64;
  const float thr = thrArr[h];

  __shared__ _Float16 Plds[64][136];  // pad 128->136
  __shared__ float rsLDS[64][4];

  // Q fragments are kt-invariant: hoist
  f16x8 qH[4][2], qL[4][2];
#pragma unroll
  for (int i = 0; i < 4; ++i)
#pragma unroll
    for (int kk = 0; kk < 2; ++kk) {
      const size_t aoff = (size_t)(m0 + i*16 + lr) * 1024 + h*64 + kk*32 + ko*8;
      qH[i][kk] = *(const f16x8*)(Qh + aoff);
      qL[i][kk] = *(const f16x8*)(Ql + aoff);
    }

  f32x4 oacc[4];
#pragma unroll
  for (int i = 0; i < 4; ++i) oacc[i] = (f32x4){0.f, 0.f, 0.f, 0.f};
  float rs[4][4];
#pragma unroll
  for (int i = 0; i < 4; ++i)
#pragma unroll
    for (int r = 0; r < 4; ++r) rs[i][r] = 0.f;

  const int d0 = wave * 16;   // PV: wave owns dims d0..d0+15

  for (int kt = half*8; kt < half*8 + 8; ++kt) {
    const int n0 = kt*128 + wave*32;   // S: wave owns keys n0..n0+31
    f32x4 sacc[4][2];
#pragma unroll
    for (int i = 0; i < 4; ++i)
#pragma unroll
      for (int j = 0; j < 2; ++j) sacc[i][j] = (f32x4){0.f, 0.f, 0.f, 0.f};

#pragma unroll
    for (int kk = 0; kk < 2; ++kk) {
      f16x8 bH[2], bL[2];
#pragma unroll
      for (int j = 0; j < 2; ++j) {
        const size_t boff = (size_t)(n0 + j*16 + lr) * 1024 + h*64 + kk*32 + ko*8;
        bH[j] = *(const f16x8*)(Kh + boff);
        bL[j] = *(const f16x8*)(Kl + boff);
      }
#pragma unroll
      for (int i = 0; i < 4; ++i)
#pragma unroll
        for (int j = 0; j < 2; ++j) {
          sacc[i][j] = __builtin_amdgcn_mfma_f32_16x16x32_f16(qL[i][kk], bL[j], sacc[i][j], 0, 0, 0);
          sacc[i][j] = __builtin_amdgcn_mfma_f32_16x16x32_f16(qH[i][kk], bL[j], sacc[i][j], 0, 0, 0);
          sacc[i][j] = __builtin_amdgcn_mfma_f32_16x16x32_f16(qL[i][kk], bH[j], sacc[i][j], 0, 0, 0);
          sacc[i][j] = __builtin_amdgcn_mfma_f32_16x16x32_f16(qH[i][kk], bH[j], sacc[i][j], 0, 0, 0);
        }
    }

    // mask + exp + P->LDS + rowsum partials
#pragma unroll
    for (int i = 0; i < 4; ++i)
#pragma unroll
      for (int j = 0; j < 2; ++j)
#pragma unroll
        for (int r = 0; r < 4; ++r) {
          const float val = sacc[i][j][r] * 0.125f;
          const float p = (val >= thr) ? __expf(val - thr - ESHIFT) : 0.f;
          rs[i][r] += p;
          Plds[i*16 + ko*4 + r][wave*32 + j*16 + lr] = (_Float16)p;
        }
    __syncthreads();

    // PV: oacc[i] over dims d0+lr, keys kt*128..+127
#pragma unroll
    for (int kk2 = 0; kk2 < 4; ++kk2) {
      f16x8 pa[4];
#pragma unroll
      for (int i = 0; i < 4; ++i)
        pa[i] = *(const f16x8*)&Plds[i*16 + lr][kk2*32 + ko*8];
      const size_t vo = (size_t)(h*64 + d0 + lr) * 2048 + kt*128 + kk2*32 + ko*8;
      const f16x8 vH = *(const f16x8*)(VtH + vo);
      const f16x8 vL = *(const f16x8*)(VtL + vo);
#pragma unroll
      for (int i = 0; i < 4; ++i) {
        oacc[i] = __builtin_amdgcn_mfma_f32_16x16x32_f16(pa[i], vL, oacc[i], 0, 0, 0);
        oacc[i] = __builtin_amdgcn_mfma_f32_16x16x32_f16(pa[i], vH, oacc[i], 0, 0, 0);
      }
    }
    __syncthreads();   // before next kt overwrites Plds
  }

  // rowsum: reduce across the 16 lanes of each ko-group, then across waves
#pragma unroll
  for (int i = 0; i < 4; ++i)
#pragma unroll
    for (int r = 0; r < 4; ++r) {
      float v = rs[i][r];
      v += __shfl_xor(v, 1); v += __shfl_xor(v, 2);
      v += __shfl_xor(v, 4); v += __shfl_xor(v, 8);
      rs[i][r] = v;
    }
  if (lr == 0) {
#pragma unroll
    for (int i = 0; i < 4; ++i)
#pragma unroll
      for (int r = 0; r < 4; ++r)
        rsLDS[i*16 + ko*4 + r][wave] = rs[i][r];
  }
  __syncthreads();

  // write partial rowsums (wave 0, lr==0 lanes cover rows via ko,i,r)
  if (wave == 0 && lr == 0) {
#pragma unroll
    for (int i = 0; i < 4; ++i)
#pragma unroll
      for (int r = 0; r < 4; ++r) {
        const int lrow = i*16 + ko*4 + r;
        prs[half*32768 + h*2048 + m0 + lrow] =
            rsLDS[lrow][0] + rsLDS[lrow][1] + rsLDS[lrow][2] + rsLDS[lrow][3];
      }
  }

  // store raw partial O
  float* __restrict__ pc = pctx + (size_t)half * PLANE;
#pragma unroll
  for (int i = 0; i < 4; ++i)
#pragma unroll
    for (int r = 0; r < 4; ++r) {
      const int lrow = i*16 + ko*4 + r;
      pc[(size_t)(m0 + lrow) * 1024 + h*64 + d0 + lr] = oacc[i][r];
    }
}

// ---------------- host ----------------
extern "C" void kernel_launch(void* const* d_in, const int* in_sizes, int n_in,
                              void* d_out, int out_size, void* d_ws, size_t ws_size,
                              hipStream_t stream)
{
  const float* x  = (const float*)d_in[0];
  const float* Wq = (const float*)d_in[1];
  const float* bq = (const float*)d_in[2];
  const float* Wk = (const float*)d_in[3];
  const float* bk = (const float*)d_in[4];
  const float* Wv = (const float*)d_in[5];
  const float* bv = (const float*)d_in[6];
  const float* Wo = (const float*)d_in[7];
  const float* bo = (const float*)d_in[8];
  float* out = (float*)d_out;
  char*  ws  = (char*)d_ws;

  const size_t MB = 1u << 20;
  _Float16* xh      = (_Float16*)(ws + 0*MB);
  _Float16* xl      = (_Float16*)(ws + 4*MB);
  _Float16* wplanes = (_Float16*)(ws + 8*MB);    // 8 x 2 MiB transposed W planes
  _Float16* Qh      = (_Float16*)(ws + 24*MB);
  _Float16* Ql      = (_Float16*)(ws + 28*MB);
  _Float16* Kh      = (_Float16*)(ws + 32*MB);
  _Float16* Kl      = (_Float16*)(ws + 36*MB);
  _Float16* VtH     = (_Float16*)(ws + 40*MB);   // [1024 dims][2048 rows]
  _Float16* VtL     = (_Float16*)(ws + 44*MB);
  _Float16* ctxh    = (_Float16*)(ws + 48*MB);
  _Float16* ctxl    = (_Float16*)(ws + 52*MB);
  const size_t base = 56*MB;
  unsigned* state = (unsigned*)(ws + base);
  float*    thr   = (float*)(ws + base + 4096);
  unsigned* ccnt  = (unsigned*)(ws + base + 8192);
  unsigned* ghist = (unsigned*)(ws + base + 16384);           // 1 MiB
  unsigned* cand  = (unsigned*)(ws + base + 16384 + 1048576); // 3 MiB
  float*    prs   = (float*)(ws + 61*MB);                     // 2 x 16 x 2048 f32
  float*    pbuf  = (float*)(ws + 64*MB);                     // 6 x 8 MiB qkv partials
  float*    pctx  = pbuf;                                     // alias planes 0,1 (after combine_qk)
  float*    pO    = pbuf + (size_t)2 * PLANE;                 // alias planes 2,3 (after combine_qk)

  split_x<<<2048, 256, 0, stream>>>(x, xh, xl);
  split_wT<<<dim3(16, 16, 4), 256, 0, stream>>>(Wq, Wk, Wv, Wo, wplanes);
  gemm_qkv_part<<<dim3(8, 16, 6), 256, 0, stream>>>(xh, xl, wplanes, pbuf);
  combine_qk<<<dim3(2048, 2), 256, 0, stream>>>(pbuf, bq, bk, Qh, Ql, Kh, Kl);
  combine_vT<<<dim3(16, 32), 256, 0, stream>>>(pbuf, bv, VtH, VtL);

  init14<<<256, 256, 0, stream>>>(ghist, ccnt);
  scores_hist<<<dim3(16, 8, HH), 512, 0, stream>>>(Qh, Ql, Kh, Kl, ghist);
  scan14<<<HH, 256, 0, stream>>>(ghist, state);
  compact_recompute<<<dim3(16, 8, HH), 512, 0, stream>>>(Qh, Ql, Kh, Kl, state, cand, ccnt);
  final_select_list<<<HH, 256, 0, stream>>>(cand, ccnt, state, thr);
  flash_pv_sk<<<dim3(32, HH, 2), 256, 0, stream>>>(Qh, Ql, Kh, Kl, VtH, VtL, thr, pctx, prs);
  combine_ctx<<<2048, 256, 0, stream>>>(pctx, prs, ctxh, ctxl);

  gemm_o_part<<<dim3(8, 16, 2), 256, 0, stream>>>(ctxh, ctxl, wplanes, pO);
  combine_o<<<2048, 256, 0, stream>>>(pO, bo, out);
}